// Round 1
// baseline (808.029 us; speedup 1.0000x reference)
//
#include <hip/hip_runtime.h>
#include <stdint.h>

// Problem constants
#define BB 16
#define NKG 1024
#define SLM 1024
#define DD 1024
#define HH 4096

typedef unsigned short u16;
typedef __attribute__((ext_vector_type(8))) short frag8;   // 8 bf16 in 4 VGPRs
typedef __attribute__((ext_vector_type(4))) float facc4;   // MFMA accumulator

__device__ __forceinline__ u16 f2bf(float f) {
  union { float f; unsigned u; } c; c.f = f;
  return (u16)((c.u + 0x7fffu + ((c.u >> 16) & 1u)) >> 16);  // RNE
}
__device__ __forceinline__ float bf2f(u16 h) {
  union { unsigned u; float f; } c; c.u = ((unsigned)h) << 16;
  return c.f;
}

// async global->LDS, 16B per lane. LDS dest must be wave-uniform base + lane*16.
__device__ __forceinline__ void async16(const u16* g, u16* l) {
  __builtin_amdgcn_global_load_lds(
      (__attribute__((address_space(1))) void*)(void*)(g),
      (__attribute__((address_space(3))) void*)(void*)(l), 16, 0, 0);
}

// ---------------- elementwise cast fp32 -> bf16 (float4 vectorized) -------------
__global__ void cast_bf16(const float* __restrict__ in, u16* __restrict__ out) {
  const long i = ((long)blockIdx.x * 256 + threadIdx.x) * 4;
  const float4 v = *(const float4*)(in + i);
  ushort4 o;
  o.x = f2bf(v.x); o.y = f2bf(v.y); o.z = f2bf(v.z); o.w = f2bf(v.w);
  *(ushort4*)(out + i) = o;
}

// ---------------- transpose + cast: in fp32 [R][C] -> out bf16 [C][R] -----------
__global__ void transpose_cast(const float* __restrict__ in, u16* __restrict__ out,
                               int R, int C, long sIn, long sOut) {
  __shared__ u16 tile[32][33];
  const int bz = blockIdx.z;
  const float* ip = in + (long)bz * sIn;
  u16* op = out + (long)bz * sOut;
  const int c0 = blockIdx.x * 32, r0 = blockIdx.y * 32;
  const int tx = threadIdx.x & 31, ty = threadIdx.x >> 5;
#pragma unroll
  for (int i = 0; i < 32; i += 8)
    tile[ty + i][tx] = f2bf(ip[(long)(r0 + ty + i) * C + c0 + tx]);
  __syncthreads();
#pragma unroll
  for (int i = 0; i < 32; i += 8)
    op[(long)(c0 + ty + i) * R + r0 + tx] = tile[tx][ty + i];
}

// ---------------- m97-style bf16 GEMM: C[M,N] = A[M,K] * Bt[N,K]^T --------------
// EPI 0: store bf16 (logits)
// EPI 1: fp32 store: v - colAux[b,col] + resid[b,row,col]   (out1 = GEMM - c + kg)
// EPI 2: bf16 store: relu(v + colAux[col])                  (h = relu(.+b1))
// EPI 3: fp32 store: v + colAux[col] + resid[row,col]       (out = ffn + b2 + out1)
template <int EPI>
__global__ void __launch_bounds__(256)
gemm_bt(const u16* __restrict__ A, const u16* __restrict__ Bt, void* __restrict__ Cv,
        const float* __restrict__ colAux, const float* __restrict__ resid,
        int N, int K, long sA, long sB, long sC, long sColAux, long sResid) {
  __shared__ u16 As[128 * 32];
  __shared__ u16 Bs[128 * 32];
  const int bz = blockIdx.z;
  const u16* Ab = A + (long)bz * sA + (long)blockIdx.y * 128 * K;
  const u16* Bb = Bt + (long)bz * sB + (long)blockIdx.x * 128 * K;
  const int tid = threadIdx.x;
  const int w = tid >> 6, l = tid & 63;
  const int wm = w >> 1, wn = w & 1;        // 2x2 wave grid, 64x64 per wave
  const int quad = l >> 4, lr = l & 15;
  const int r0 = tid >> 2;                  // staging row (0..63), +64 for 2nd load
  const int cc = (tid & 3) * 8;             // staging col (bf16 elems)

  facc4 zero = {0.f, 0.f, 0.f, 0.f};
  facc4 acc[4][4];
#pragma unroll
  for (int i = 0; i < 4; ++i)
#pragma unroll
    for (int j = 0; j < 4; ++j) acc[i][j] = zero;

  for (int k0 = 0; k0 < K; k0 += 32) {
    __syncthreads();
    async16(Ab + (long)r0 * K + k0 + cc, &As[tid * 8]);
    async16(Ab + (long)(r0 + 64) * K + k0 + cc, &As[2048 + tid * 8]);
    async16(Bb + (long)r0 * K + k0 + cc, &Bs[tid * 8]);
    async16(Bb + (long)(r0 + 64) * K + k0 + cc, &Bs[2048 + tid * 8]);
    __syncthreads();
    frag8 af[4], bfr[4];
#pragma unroll
    for (int mt = 0; mt < 4; ++mt)
      af[mt] = *(const frag8*)&As[(wm * 64 + mt * 16 + lr) * 32 + quad * 8];
#pragma unroll
    for (int nt = 0; nt < 4; ++nt)
      bfr[nt] = *(const frag8*)&Bs[(wn * 64 + nt * 16 + lr) * 32 + quad * 8];
#pragma unroll
    for (int mt = 0; mt < 4; ++mt)
#pragma unroll
      for (int nt = 0; nt < 4; ++nt)
        acc[mt][nt] = __builtin_amdgcn_mfma_f32_16x16x32_bf16(af[mt], bfr[nt],
                                                              acc[mt][nt], 0, 0, 0);
  }

  const int rowB = blockIdx.y * 128 + wm * 64;
  const int colB = blockIdx.x * 128 + wn * 64;
#pragma unroll
  for (int mt = 0; mt < 4; ++mt) {
#pragma unroll
    for (int nt = 0; nt < 4; ++nt) {
      const int col = colB + nt * 16 + lr;
      float ca = 0.f;
      if (EPI != 0) ca = colAux[(long)bz * sColAux + col];
#pragma unroll
      for (int i = 0; i < 4; ++i) {
        const int row = rowB + mt * 16 + quad * 4 + i;   // C/D: col=lane&15, row=quad*4+reg
        const long off = (long)bz * sC + (long)row * N + col;
        const float v = acc[mt][nt][i];
        if (EPI == 0) {
          ((u16*)Cv)[off] = f2bf(v);
        } else if (EPI == 1) {
          ((float*)Cv)[off] = v - ca + resid[(long)bz * sResid + (long)row * N + col];
        } else if (EPI == 2) {
          ((u16*)Cv)[off] = f2bf(fmaxf(v + ca, 0.f));
        } else {
          ((float*)Cv)[off] = v + ca + resid[(long)row * N + col];
        }
      }
    }
  }
}

// ------------- column logsumexp over n (axis=1) of bf16 logits [b][n][s] --------
#define NCH 8
__global__ void lse_partial(const u16* __restrict__ logits, float* __restrict__ pm,
                            float* __restrict__ pl) {
  const int s = blockIdx.x * 256 + threadIdx.x;
  const int ch = blockIdx.y, b = blockIdx.z;
  const u16* p = logits + ((long)b << 20) + s;
  float m = -1e30f, lsum = 0.f;
  const int n0 = ch * (NKG / NCH);
  for (int n = n0; n < n0 + NKG / NCH; ++n) {
    const float x = bf2f(p[(long)n << 10]);
    const float nm = fmaxf(m, x);
    lsum = lsum * __expf(m - nm) + __expf(x - nm);
    m = nm;
  }
  const int idx = ((b << 3) + ch) * SLM + s;
  pm[idx] = m; pl[idx] = lsum;
}

__global__ void lse_combine(const float* __restrict__ pm, const float* __restrict__ pl,
                            float* __restrict__ L) {
  const int s = blockIdx.x * 256 + threadIdx.x;
  const int b = blockIdx.y;
  float M = -1e30f;
#pragma unroll
  for (int ch = 0; ch < NCH; ++ch) M = fmaxf(M, pm[((b << 3) + ch) * SLM + s]);
  float sum = 0.f;
#pragma unroll
  for (int ch = 0; ch < NCH; ++ch) {
    const int idx = ((b << 3) + ch) * SLM + s;
    sum += pl[idx] * __expf(pm[idx] - M);
  }
  L[b * SLM + s] = M + __logf(sum);
}

// ------------- c[b][d] = sum_s L[b][s] * lm[b][s][d] ---------------------------
__global__ void c_partial(const float* __restrict__ lm, const float* __restrict__ L,
                          float* __restrict__ pc) {
  const int d = blockIdx.x * 256 + threadIdx.x;
  const int ch = blockIdx.y, b = blockIdx.z;
  const float* lp = lm + ((long)b << 20);
  const float* Lp = L + (b << 10);
  float acc = 0.f;
  const int s0 = ch * (SLM / NCH);
  for (int s = s0; s < s0 + SLM / NCH; ++s)
    acc = fmaf(Lp[s], lp[((long)s << 10) + d], acc);
  pc[((b << 3) + ch) * DD + d] = acc;
}

__global__ void c_combine(const float* __restrict__ pc, float* __restrict__ c) {
  const int d = blockIdx.x * 256 + threadIdx.x;
  const int b = blockIdx.y;
  float s = 0.f;
#pragma unroll
  for (int ch = 0; ch < NCH; ++ch) s += pc[((b << 3) + ch) * DD + d];
  c[(b << 10) + d] = s;
}

// ------------- row LayerNorm over D=1024, fp32 in -> bf16 out -------------------
__global__ void layernorm_rows(const float* __restrict__ x, const float* __restrict__ gamma,
                               const float* __restrict__ beta, u16* __restrict__ y) {
  const long row = blockIdx.x;
  const int t = threadIdx.x;
  const float4 v = ((const float4*)(x + (row << 10)))[t];
  float s = v.x + v.y + v.z + v.w;
  float q = v.x * v.x + v.y * v.y + v.z * v.z + v.w * v.w;
#pragma unroll
  for (int off = 32; off > 0; off >>= 1) {
    s += __shfl_xor(s, off);
    q += __shfl_xor(q, off);
  }
  __shared__ float ss[4], qq[4];
  if ((t & 63) == 0) { ss[t >> 6] = s; qq[t >> 6] = q; }
  __syncthreads();
  s = ss[0] + ss[1] + ss[2] + ss[3];
  q = qq[0] + qq[1] + qq[2] + qq[3];
  const float mu = s * (1.f / 1024.f);
  const float rs = rsqrtf(q * (1.f / 1024.f) - mu * mu + 1e-6f);
  const float4 g = ((const float4*)gamma)[t];
  const float4 bb = ((const float4*)beta)[t];
  ushort4 o;
  o.x = f2bf((v.x - mu) * rs * g.x + bb.x);
  o.y = f2bf((v.y - mu) * rs * g.y + bb.y);
  o.z = f2bf((v.z - mu) * rs * g.z + bb.z);
  o.w = f2bf((v.w - mu) * rs * g.w + bb.w);
  ((ushort4*)(y + (row << 10)))[t] = o;
}

extern "C" void kernel_launch(void* const* d_in, const int* in_sizes, int n_in,
                              void* d_out, int out_size, void* d_ws, size_t ws_size,
                              hipStream_t stream) {
  (void)in_sizes; (void)n_in; (void)out_size;
  const float* kg = (const float*)d_in[0];
  const float* lm = (const float*)d_in[1];
  // d_in[2] attention_mask: log(mask+eps) is constant along the softmax axis
  // (axis=1) and cancels exactly in log_softmax -> unused.
  const float* W1 = (const float*)d_in[3];
  const float* b1 = (const float*)d_in[4];
  const float* W2 = (const float*)d_in[5];
  const float* b2 = (const float*)d_in[6];
  const float* gamma = (const float*)d_in[7];
  const float* beta = (const float*)d_in[8];
  float* out = (float*)d_out;
  char* ws = (char*)d_ws;

  const long SZ = 33554432;  // 16M bf16 = one [16][1024][1024] bf16 tensor
  u16* kg_bf  = (u16*)(ws);
  u16* lm_bf  = (u16*)(ws + SZ);
  u16* lmT    = (u16*)(ws + 2 * SZ);         // [b][d][s]
  u16* logits = (u16*)(ws + 3 * SZ);         // [b][n][s]
  u16* h      = (u16*)(ws);                  // reuse kg_bf..logits after K3
  u16* out1n  = (u16*)(ws + 4 * SZ);
  u16* W1t    = (u16*)(ws + 4 * SZ + SZ);            // [H][D]
  u16* W2t    = (u16*)(ws + 4 * SZ + SZ + 8388608);  // [D][H]
  float* Lse  = (float*)(ws + 4 * SZ + SZ + 16777216);
  float* cvec = (float*)(ws + 4 * SZ + SZ + 16777216 + 65536);
  float* pm   = (float*)(ws + 4 * SZ + SZ + 16777216 + 131072);
  float* pl   = (float*)(ws + 4 * SZ + SZ + 16777216 + 131072 + 524288);
  float* pc   = (float*)(ws + 4 * SZ + SZ + 16777216 + 131072 + 1048576);
  float* out1 = out;  // out1 lives in d_out; final GEMM does in-place +=

  if (ws_size < (size_t)(4 * SZ + SZ + 16777216 + 131072 + 1572864)) return;  // ~186MB

  // Stage 0: casts & transposes
  cast_bf16<<<16384, 256, 0, stream>>>(kg, kg_bf);
  cast_bf16<<<16384, 256, 0, stream>>>(lm, lm_bf);
  transpose_cast<<<dim3(32, 32, 16), 256, 0, stream>>>(lm, lmT, SLM, DD, 1048576, 1048576);
  transpose_cast<<<dim3(128, 32, 1), 256, 0, stream>>>(W1, W1t, DD, HH, 0, 0);
  transpose_cast<<<dim3(32, 128, 1), 256, 0, stream>>>(W2, W2t, HH, DD, 0, 0);

  // K1: logits = kg @ lm^T  (bf16 out)
  gemm_bt<0><<<dim3(8, 8, 16), 256, 0, stream>>>(kg_bf, lm_bf, logits, nullptr, nullptr,
                                                 SLM, DD, 1048576, 1048576, 1048576, 0, 0);
  // K2: L[b,s] = logsumexp_n logits ; c[b,d] = sum_s L*lm
  lse_partial<<<dim3(4, NCH, 16), 256, 0, stream>>>(logits, pm, pl);
  lse_combine<<<dim3(4, 16), 256, 0, stream>>>(pm, pl, Lse);
  c_partial<<<dim3(4, NCH, 16), 256, 0, stream>>>(lm, Lse, pc);
  c_combine<<<dim3(4, 16), 256, 0, stream>>>(pc, cvec);
  // K3: out1 = logits @ lm - c + kg   (fp32, into d_out)
  gemm_bt<1><<<dim3(8, 8, 16), 256, 0, stream>>>(logits, lmT, out1, cvec, kg,
                                                 DD, SLM, 1048576, 1048576, 1048576, 1024, 1048576);
  // K4: layernorm rows -> bf16
  layernorm_rows<<<16384, 256, 0, stream>>>(out1, gamma, beta, out1n);
  // K5: h = relu(out1n @ W1 + b1)  (bf16)
  gemm_bt<2><<<dim3(32, 128, 1), 256, 0, stream>>>(out1n, W1t, h, b1, nullptr,
                                                   HH, DD, 0, 0, 0, 0, 0);
  // K6: out = h @ W2 + b2 + out1   (fp32, in-place on d_out)
  gemm_bt<3><<<dim3(8, 128, 1), 256, 0, stream>>>(h, W2t, out, b2, out1,
                                                  DD, HH, 0, 0, 0, 0, 0);
}

// Round 2
// 589.589 us; speedup vs baseline: 1.3705x; 1.3705x over previous
//
#include <hip/hip_runtime.h>
#include <stdint.h>

// Problem constants
#define BB 16
#define NKG 1024
#define SLM 1024
#define DD 1024
#define HH 4096

typedef unsigned short u16;
typedef uint8_t u8;
typedef __attribute__((ext_vector_type(8))) short frag8;   // 8 bf16 in 4 VGPRs
typedef __attribute__((ext_vector_type(4))) float facc4;   // MFMA accumulator
typedef __attribute__((ext_vector_type(4))) int i32x4;
typedef __attribute__((ext_vector_type(8))) int i32x8;     // 32B fp8 A/B operand

__device__ __forceinline__ u16 f2bf(float f) {
  union { float f; unsigned u; } c; c.f = f;
  return (u16)((c.u + 0x7fffu + ((c.u >> 16) & 1u)) >> 16);  // RNE
}
__device__ __forceinline__ float bf2f(u16 h) {
  union { unsigned u; float f; } c; c.u = ((unsigned)h) << 16;
  return c.f;
}
__device__ __forceinline__ u8 f2fp8(float f) {
  int p = __builtin_amdgcn_cvt_pk_fp8_f32(f, f, 0, false);  // OCP e4m3 on gfx950
  return (u8)(p & 0xff);
}

// async global->LDS, 16B per lane. LDS dest must be wave-uniform base + lane*16.
__device__ __forceinline__ void async16(const void* g, void* l) {
  __builtin_amdgcn_global_load_lds(
      (__attribute__((address_space(1))) void*)(void*)(g),
      (__attribute__((address_space(3))) void*)(void*)(l), 16, 0, 0);
}

// ---------------- elementwise cast fp32 -> bf16 (float4 vectorized) -------------
__global__ void cast_bf16(const float* __restrict__ in, u16* __restrict__ out) {
  const long i = ((long)blockIdx.x * 256 + threadIdx.x) * 4;
  const float4 v = *(const float4*)(in + i);
  ushort4 o;
  o.x = f2bf(v.x); o.y = f2bf(v.y); o.z = f2bf(v.z); o.w = f2bf(v.w);
  *(ushort4*)(out + i) = o;
}

// ---------------- transpose + cast: in fp32 [R][C] -> out bf16 [C][R] -----------
__global__ void transpose_cast(const float* __restrict__ in, u16* __restrict__ out,
                               int R, int C, long sIn, long sOut) {
  __shared__ u16 tile[32][33];
  const int bz = blockIdx.z;
  const float* ip = in + (long)bz * sIn;
  u16* op = out + (long)bz * sOut;
  const int c0 = blockIdx.x * 32, r0 = blockIdx.y * 32;
  const int tx = threadIdx.x & 31, ty = threadIdx.x >> 5;
#pragma unroll
  for (int i = 0; i < 32; i += 8)
    tile[ty + i][tx] = f2bf(ip[(long)(r0 + ty + i) * C + c0 + tx]);
  __syncthreads();
#pragma unroll
  for (int i = 0; i < 32; i += 8)
    op[(long)(c0 + ty + i) * R + r0 + tx] = tile[tx][ty + i];
}

// ---------------- transpose + cast: in fp32 [R][C] -> out fp8 [C][R] ------------
__global__ void transpose_cast_fp8(const float* __restrict__ in, u8* __restrict__ out,
                                   int R, int C) {
  __shared__ u8 tile[32][36];
  const int c0 = blockIdx.x * 32, r0 = blockIdx.y * 32;
  const int tx = threadIdx.x & 31, ty = threadIdx.x >> 5;
#pragma unroll
  for (int i = 0; i < 32; i += 8)
    tile[ty + i][tx] = f2fp8(in[(long)(r0 + ty + i) * C + c0 + tx]);
  __syncthreads();
#pragma unroll
  for (int i = 0; i < 32; i += 8)
    out[(long)(c0 + ty + i) * R + r0 + tx] = tile[tx][ty + i];
}

// ---------------- bf16 GEMM (swizzled LDS): C[M,N] = A[M,K] * Bt[N,K]^T ---------
// EPI 0: store bf16 (logits)
// EPI 1: fp32 store: v - colAux[b,col] + resid[b,row,col]   (out1 = GEMM - c + kg)
template <int EPI>
__global__ void __launch_bounds__(256)
gemm_bt(const u16* __restrict__ A, const u16* __restrict__ Bt, void* __restrict__ Cv,
        const float* __restrict__ colAux, const float* __restrict__ resid,
        int N, int K, long sA, long sB, long sC, long sColAux, long sResid) {
  __shared__ u16 As[128 * 32];
  __shared__ u16 Bs[128 * 32];
  const int bz = blockIdx.z;
  const u16* Ab = A + (long)bz * sA + (long)blockIdx.y * 128 * K;
  const u16* Bb = Bt + (long)bz * sB + (long)blockIdx.x * 128 * K;
  const int tid = threadIdx.x;
  const int w = tid >> 6, l = tid & 63;
  const int wm = w >> 1, wn = w & 1;        // 2x2 wave grid, 64x64 per wave
  const int quad = l >> 4, lr = l & 15;
  const int r0 = tid >> 2;                  // staging row (0..63), +64 for 2nd load
  // XOR-swizzled staging chunk: LDS[row][c] = global[row][c ^ ((row>>1)&3)]
  const int cc = ((tid & 3) ^ ((r0 >> 1) & 3)) * 8;  // global chunk (elems)
  // frag-read chunk: global chunk `quad` lives at LDS chunk quad^((row>>1)&3);
  // (row>>1)&3 == (lr>>1)&3 for all mt (row = wm*64+mt*16+lr).
  const int qs = (quad ^ ((lr >> 1) & 3)) * 8;

  facc4 zero = {0.f, 0.f, 0.f, 0.f};
  facc4 acc[4][4];
#pragma unroll
  for (int i = 0; i < 4; ++i)
#pragma unroll
    for (int j = 0; j < 4; ++j) acc[i][j] = zero;

  for (int k0 = 0; k0 < K; k0 += 32) {
    __syncthreads();
    async16(Ab + (long)r0 * K + k0 + cc, &As[tid * 8]);
    async16(Ab + (long)(r0 + 64) * K + k0 + cc, &As[2048 + tid * 8]);
    async16(Bb + (long)r0 * K + k0 + cc, &Bs[tid * 8]);
    async16(Bb + (long)(r0 + 64) * K + k0 + cc, &Bs[2048 + tid * 8]);
    __syncthreads();
    frag8 af[4], bfr[4];
#pragma unroll
    for (int mt = 0; mt < 4; ++mt)
      af[mt] = *(const frag8*)&As[(wm * 64 + mt * 16 + lr) * 32 + qs];
#pragma unroll
    for (int nt = 0; nt < 4; ++nt)
      bfr[nt] = *(const frag8*)&Bs[(wn * 64 + nt * 16 + lr) * 32 + qs];
#pragma unroll
    for (int mt = 0; mt < 4; ++mt)
#pragma unroll
      for (int nt = 0; nt < 4; ++nt)
        acc[mt][nt] = __builtin_amdgcn_mfma_f32_16x16x32_bf16(af[mt], bfr[nt],
                                                              acc[mt][nt], 0, 0, 0);
  }

  const int rowB = blockIdx.y * 128 + wm * 64;
  const int colB = blockIdx.x * 128 + wn * 64;
#pragma unroll
  for (int mt = 0; mt < 4; ++mt) {
#pragma unroll
    for (int nt = 0; nt < 4; ++nt) {
      const int col = colB + nt * 16 + lr;
      float ca = 0.f;
      if (EPI != 0) ca = colAux[(long)bz * sColAux + col];
#pragma unroll
      for (int i = 0; i < 4; ++i) {
        const int row = rowB + mt * 16 + quad * 4 + i;   // C/D: col=lane&15, row=quad*4+reg
        const long off = (long)bz * sC + (long)row * N + col;
        const float v = acc[mt][nt][i];
        if (EPI == 0) {
          ((u16*)Cv)[off] = f2bf(v);
        } else {
          ((float*)Cv)[off] = v - ca + resid[(long)bz * sResid + (long)row * N + col];
        }
      }
    }
  }
}

// ------------- MX-fp8 GEMM (scale=1.0): C[M,N] = A[M,K] * Bt[N,K]^T -------------
// BK=128 fp8, mfma_scale_f32_16x16x128_f8f6f4 (2x bf16 MFMA rate).
// EPI 2: fp8 store relu(v + colAux[col])          (h = relu(.+b1))
// EPI 3: fp32 store v + colAux[col] + resid[off]  (out = ffn + b2 + out1)
template <int EPI>
__global__ void __launch_bounds__(256)
gemm_f8(const u8* __restrict__ A, const u8* __restrict__ Bt, void* __restrict__ Cv,
        const float* __restrict__ colAux, const float* __restrict__ resid,
        int N, int K) {
  __shared__ u8 As[128 * 128];
  __shared__ u8 Bs[128 * 128];
  const u8* Ab = A + (long)blockIdx.y * 128 * K;
  const u8* Bb = Bt + (long)blockIdx.x * 128 * K;
  const int tid = threadIdx.x;
  const int w = tid >> 6, l = tid & 63;
  const int wm = w >> 1, wn = w & 1;
  const int quad = l >> 4, lr = l & 15;
  const int sr = tid >> 3;                                   // staging row (0..31)
  const int sc = ((tid & 7) ^ ((tid >> 3) & 7)) * 16;        // swizzled global chunk (bytes)
  // frag-read: global 16B chunk c lives at LDS chunk c^(row&7); row&7 == lr&7.
  const int qb = ((2 * quad) ^ (lr & 7)) * 16;               // first chunk byte offset
  // second chunk (2q+1)^(lr&7) == ((2q)^(lr&7))^1 -> byte offset qb^16

  facc4 zero = {0.f, 0.f, 0.f, 0.f};
  facc4 acc[4][4];
#pragma unroll
  for (int i = 0; i < 4; ++i)
#pragma unroll
    for (int j = 0; j < 4; ++j) acc[i][j] = zero;

  for (int k0 = 0; k0 < K; k0 += 128) {
    __syncthreads();
#pragma unroll
    for (int i = 0; i < 4; ++i) {
      async16(Ab + (long)(sr + 32 * i) * K + k0 + sc, &As[i * 4096 + tid * 16]);
      async16(Bb + (long)(sr + 32 * i) * K + k0 + sc, &Bs[i * 4096 + tid * 16]);
    }
    __syncthreads();
    i32x8 af[4], bfr[4];
#pragma unroll
    for (int mt = 0; mt < 4; ++mt) {
      const u8* base = &As[(wm * 64 + mt * 16 + lr) * 128];
      i32x4 lo = *(const i32x4*)(base + qb);
      i32x4 hi = *(const i32x4*)(base + (qb ^ 16));
      af[mt] = i32x8{lo.x, lo.y, lo.z, lo.w, hi.x, hi.y, hi.z, hi.w};
    }
#pragma unroll
    for (int nt = 0; nt < 4; ++nt) {
      const u8* base = &Bs[(wn * 64 + nt * 16 + lr) * 128];
      i32x4 lo = *(const i32x4*)(base + qb);
      i32x4 hi = *(const i32x4*)(base + (qb ^ 16));
      bfr[nt] = i32x8{lo.x, lo.y, lo.z, lo.w, hi.x, hi.y, hi.z, hi.w};
    }
#pragma unroll
    for (int mt = 0; mt < 4; ++mt)
#pragma unroll
      for (int nt = 0; nt < 4; ++nt)
        acc[mt][nt] = __builtin_amdgcn_mfma_scale_f32_16x16x128_f8f6f4(
            af[mt], bfr[nt], acc[mt][nt], 0, 0,   // cbsz=0 (A fp8), blgp=0 (B fp8)
            0, 0x7F7F7F7F, 0, 0x7F7F7F7F);        // E8M0 scale 127 -> 1.0
  }

  const int rowB = blockIdx.y * 128 + wm * 64;
  const int colB = blockIdx.x * 128 + wn * 64;
#pragma unroll
  for (int mt = 0; mt < 4; ++mt) {
#pragma unroll
    for (int nt = 0; nt < 4; ++nt) {
      const int col = colB + nt * 16 + lr;
      const float ca = colAux[col];
#pragma unroll
      for (int i = 0; i < 4; ++i) {
        const int row = rowB + mt * 16 + quad * 4 + i;
        const long off = (long)row * N + col;
        const float v = acc[mt][nt][i] + ca;
        if (EPI == 2) {
          ((u8*)Cv)[off] = f2fp8(fmaxf(v, 0.f));
        } else {
          ((float*)Cv)[off] = v + resid[off];
        }
      }
    }
  }
}

// ------------- column logsumexp over n (axis=1) of bf16 logits [b][n][s] --------
#define NCH 8
__global__ void lse_partial(const u16* __restrict__ logits, float* __restrict__ pm,
                            float* __restrict__ pl) {
  const int s = blockIdx.x * 256 + threadIdx.x;
  const int ch = blockIdx.y, b = blockIdx.z;
  const u16* p = logits + ((long)b << 20) + s;
  float m = -1e30f, lsum = 0.f;
  const int n0 = ch * (NKG / NCH);
  for (int n = n0; n < n0 + NKG / NCH; ++n) {
    const float x = bf2f(p[(long)n << 10]);
    const float nm = fmaxf(m, x);
    lsum = lsum * __expf(m - nm) + __expf(x - nm);
    m = nm;
  }
  const int idx = ((b << 3) + ch) * SLM + s;
  pm[idx] = m; pl[idx] = lsum;
}

__global__ void lse_combine(const float* __restrict__ pm, const float* __restrict__ pl,
                            float* __restrict__ L) {
  const int s = blockIdx.x * 256 + threadIdx.x;
  const int b = blockIdx.y;
  float M = -1e30f;
#pragma unroll
  for (int ch = 0; ch < NCH; ++ch) M = fmaxf(M, pm[((b << 3) + ch) * SLM + s]);
  float sum = 0.f;
#pragma unroll
  for (int ch = 0; ch < NCH; ++ch) {
    const int idx = ((b << 3) + ch) * SLM + s;
    sum += pl[idx] * __expf(pm[idx] - M);
  }
  L[b * SLM + s] = M + __logf(sum);
}

// ------------- c[b][d] = sum_s L[b][s] * lm[b][s][d] ---------------------------
__global__ void c_partial(const float* __restrict__ lm, const float* __restrict__ L,
                          float* __restrict__ pc) {
  const int d = blockIdx.x * 256 + threadIdx.x;
  const int ch = blockIdx.y, b = blockIdx.z;
  const float* lp = lm + ((long)b << 20);
  const float* Lp = L + (b << 10);
  float acc = 0.f;
  const int s0 = ch * (SLM / NCH);
  for (int s = s0; s < s0 + SLM / NCH; ++s)
    acc = fmaf(Lp[s], lp[((long)s << 10) + d], acc);
  pc[((b << 3) + ch) * DD + d] = acc;
}

__global__ void c_combine(const float* __restrict__ pc, float* __restrict__ c) {
  const int d = blockIdx.x * 256 + threadIdx.x;
  const int b = blockIdx.y;
  float s = 0.f;
#pragma unroll
  for (int ch = 0; ch < NCH; ++ch) s += pc[((b << 3) + ch) * DD + d];
  c[(b << 10) + d] = s;
}

// ------------- row LayerNorm over D=1024, fp32 in -> fp8 out --------------------
__global__ void layernorm_rows(const float* __restrict__ x, const float* __restrict__ gamma,
                               const float* __restrict__ beta, u8* __restrict__ y) {
  const long row = blockIdx.x;
  const int t = threadIdx.x;
  const float4 v = ((const float4*)(x + (row << 10)))[t];
  float s = v.x + v.y + v.z + v.w;
  float q = v.x * v.x + v.y * v.y + v.z * v.z + v.w * v.w;
#pragma unroll
  for (int off = 32; off > 0; off >>= 1) {
    s += __shfl_xor(s, off);
    q += __shfl_xor(q, off);
  }
  __shared__ float ss[4], qq[4];
  if ((t & 63) == 0) { ss[t >> 6] = s; qq[t >> 6] = q; }
  __syncthreads();
  s = ss[0] + ss[1] + ss[2] + ss[3];
  q = qq[0] + qq[1] + qq[2] + qq[3];
  const float mu = s * (1.f / 1024.f);
  const float rs = rsqrtf(q * (1.f / 1024.f) - mu * mu + 1e-6f);
  const float4 g = ((const float4*)gamma)[t];
  const float4 bb = ((const float4*)beta)[t];
  int p = __builtin_amdgcn_cvt_pk_fp8_f32((v.x - mu) * rs * g.x + bb.x,
                                          (v.y - mu) * rs * g.y + bb.y, 0, false);
  p = __builtin_amdgcn_cvt_pk_fp8_f32((v.z - mu) * rs * g.z + bb.z,
                                      (v.w - mu) * rs * g.w + bb.w, p, true);
  ((int*)(y + (row << 10)))[t] = p;
}

extern "C" void kernel_launch(void* const* d_in, const int* in_sizes, int n_in,
                              void* d_out, int out_size, void* d_ws, size_t ws_size,
                              hipStream_t stream) {
  (void)in_sizes; (void)n_in; (void)out_size;
  const float* kg = (const float*)d_in[0];
  const float* lm = (const float*)d_in[1];
  // d_in[2] attention_mask: log(mask+eps) is constant along the softmax axis
  // (axis=1) and cancels exactly in log_softmax -> unused.
  const float* W1 = (const float*)d_in[3];
  const float* b1 = (const float*)d_in[4];
  const float* W2 = (const float*)d_in[5];
  const float* b2 = (const float*)d_in[6];
  const float* gamma = (const float*)d_in[7];
  const float* beta = (const float*)d_in[8];
  float* out = (float*)d_out;
  char* ws = (char*)d_ws;

  const long SZ = 33554432;  // 32MB: one [16][1024][1024] bf16 tensor
  u16* kg_bf  = (u16*)(ws);                  // needed through K1
  u16* lm_bf  = (u16*)(ws + SZ);             // needed through K1
  u16* lmT    = (u16*)(ws + 2 * SZ);         // [b][d][s], through K3
  u16* logits = (u16*)(ws + 3 * SZ);         // [b][n][s], through K3
  u8*  h      = (u8*)(ws);                   // [16384][4096] fp8, 64MB; reuse after K3
  u8*  out1n  = (u8*)(ws + 4 * SZ);          // [16384][1024] fp8, 16MB
  u8*  W1t    = (u8*)(ws + 4 * SZ + 16777216);             // [H][D] fp8, 4MB
  u8*  W2t    = (u8*)(ws + 4 * SZ + 16777216 + 4194304);   // [D][H] fp8, 4MB
  char* smalls = ws + 4 * SZ + 16777216 + 8388608;
  float* Lse  = (float*)(smalls);
  float* cvec = (float*)(smalls + 65536);
  float* pm   = (float*)(smalls + 131072);
  float* pl   = (float*)(smalls + 131072 + 524288);
  float* pc   = (float*)(smalls + 131072 + 1048576);
  float* out1 = out;  // out1 lives in d_out; final GEMM reads+writes in place

  if (ws_size < (size_t)(4 * SZ + 16777216 + 8388608 + 131072 + 1572864)) return;

  // Stage 0: casts & transposes
  cast_bf16<<<16384, 256, 0, stream>>>(kg, kg_bf);
  cast_bf16<<<16384, 256, 0, stream>>>(lm, lm_bf);
  transpose_cast<<<dim3(32, 32, 16), 256, 0, stream>>>(lm, lmT, SLM, DD, 1048576, 1048576);
  transpose_cast_fp8<<<dim3(128, 32, 1), 256, 0, stream>>>(W1, W1t, DD, HH);
  transpose_cast_fp8<<<dim3(32, 128, 1), 256, 0, stream>>>(W2, W2t, HH, DD);

  // K1: logits = kg @ lm^T  (bf16 out)
  gemm_bt<0><<<dim3(8, 8, 16), 256, 0, stream>>>(kg_bf, lm_bf, logits, nullptr, nullptr,
                                                 SLM, DD, 1048576, 1048576, 1048576, 0, 0);
  // K2: L[b,s] = logsumexp_n logits ; c[b,d] = sum_s L*lm
  lse_partial<<<dim3(4, NCH, 16), 256, 0, stream>>>(logits, pm, pl);
  lse_combine<<<dim3(4, 16), 256, 0, stream>>>(pm, pl, Lse);
  c_partial<<<dim3(4, NCH, 16), 256, 0, stream>>>(lm, Lse, pc);
  c_combine<<<dim3(4, 16), 256, 0, stream>>>(pc, cvec);
  // K3: out1 = logits @ lm - c + kg   (fp32, into d_out)
  gemm_bt<1><<<dim3(8, 8, 16), 256, 0, stream>>>(logits, lmT, out1, cvec, kg,
                                                 DD, SLM, 1048576, 1048576, 1048576, 1024, 1048576);
  // K4: layernorm rows -> fp8
  layernorm_rows<<<16384, 256, 0, stream>>>(out1, gamma, beta, out1n);
  // K5: h = relu(out1n @ W1 + b1)  (fp8 in/out, MX-fp8 MFMA)
  gemm_f8<2><<<dim3(32, 128, 1), 256, 0, stream>>>(out1n, W1t, h, b1, nullptr, HH, DD);
  // K6: out = h @ W2 + b2 + out1   (fp32, in-place on d_out)
  gemm_f8<3><<<dim3(8, 128, 1), 256, 0, stream>>>(h, W2t, out, b2, out1, DD, HH);
}

// Round 3
// 512.528 us; speedup vs baseline: 1.5766x; 1.1504x over previous
//
#include <hip/hip_runtime.h>
#include <stdint.h>

// Problem constants
#define BB 16
#define NKG 1024
#define SLM 1024
#define DD 1024
#define HH 4096

typedef unsigned short u16;
typedef uint8_t u8;
typedef __attribute__((ext_vector_type(8))) short frag8;   // 8 bf16 in 4 VGPRs
typedef __attribute__((ext_vector_type(4))) float facc4;   // MFMA accumulator
typedef __attribute__((ext_vector_type(4))) int i32x4;
typedef __attribute__((ext_vector_type(8))) int i32x8;     // 32B fp8 A/B operand

__device__ __forceinline__ u16 f2bf(float f) {
  union { float f; unsigned u; } c; c.f = f;
  return (u16)((c.u + 0x7fffu + ((c.u >> 16) & 1u)) >> 16);  // RNE
}
__device__ __forceinline__ float bf2f(u16 h) {
  union { unsigned u; float f; } c; c.u = ((unsigned)h) << 16;
  return c.f;
}
__device__ __forceinline__ u8 f2fp8(float f) {
  int p = __builtin_amdgcn_cvt_pk_fp8_f32(f, f, 0, false);  // OCP e4m3 on gfx950
  return (u8)(p & 0xff);
}

// async global->LDS, 16B per lane. LDS dest must be wave-uniform base + lane*16.
__device__ __forceinline__ void async16(const void* g, void* l) {
  __builtin_amdgcn_global_load_lds(
      (__attribute__((address_space(1))) void*)(void*)(g),
      (__attribute__((address_space(3))) void*)(void*)(l), 16, 0, 0);
}

// ---------------- elementwise cast fp32 -> bf16 (float4 vectorized) -------------
__global__ void cast_bf16(const float* __restrict__ in, u16* __restrict__ out) {
  const long i = ((long)blockIdx.x * 256 + threadIdx.x) * 4;
  const float4 v = *(const float4*)(in + i);
  ushort4 o;
  o.x = f2bf(v.x); o.y = f2bf(v.y); o.z = f2bf(v.z); o.w = f2bf(v.w);
  *(ushort4*)(out + i) = o;
}

// ------- fused: lm fp32 [b][s][d] -> lm_bf (same layout) + lmT [b][d][s] --------
__global__ void lm_prep(const float* __restrict__ in, u16* __restrict__ straight,
                        u16* __restrict__ transposed) {
  __shared__ u16 tile[32][33];
  const int bz = blockIdx.z;
  const float* ip = in + ((long)bz << 20);
  u16* sp = straight + ((long)bz << 20);
  u16* tp = transposed + ((long)bz << 20);
  const int c0 = blockIdx.x * 32, r0 = blockIdx.y * 32;  // c over d, r over s
  const int tx = threadIdx.x & 31, ty = threadIdx.x >> 5;
#pragma unroll
  for (int i = 0; i < 32; i += 8) {
    const u16 v = f2bf(ip[(long)(r0 + ty + i) * DD + c0 + tx]);
    sp[(long)(r0 + ty + i) * DD + c0 + tx] = v;
    tile[ty + i][tx] = v;
  }
  __syncthreads();
#pragma unroll
  for (int i = 0; i < 32; i += 8)
    tp[(long)(c0 + ty + i) * SLM + r0 + tx] = tile[tx][ty + i];
}

// ---------------- transpose + cast: in fp32 [R][C] -> out fp8 [C][R] ------------
__global__ void transpose_cast_fp8(const float* __restrict__ in, u8* __restrict__ out,
                                   int R, int C) {
  __shared__ u8 tile[32][36];
  const int c0 = blockIdx.x * 32, r0 = blockIdx.y * 32;
  const int tx = threadIdx.x & 31, ty = threadIdx.x >> 5;
#pragma unroll
  for (int i = 0; i < 32; i += 8)
    tile[ty + i][tx] = f2fp8(in[(long)(r0 + ty + i) * C + c0 + tx]);
  __syncthreads();
#pragma unroll
  for (int i = 0; i < 32; i += 8)
    out[(long)(c0 + ty + i) * R + r0 + tx] = tile[tx][ty + i];
}

// --------- bf16 GEMM, BK=64, swizzled LDS, XCD-aware batched decode -------------
// Grid: 1024 linear blocks -> (bz, by, bx); each XCD owns 2 whole batches.
// EPI 0: store bf16 (logits)
// EPI 1: bf16 store: v - colAux[b,col] + resid[b,row,col]   (out1 = GEMM - c + kg)
template <int EPI>
__global__ void __launch_bounds__(256)
gemm_bt(const u16* __restrict__ A, const u16* __restrict__ Bt, void* __restrict__ Cv,
        const float* __restrict__ colAux, const float* __restrict__ resid,
        int N, int K, long sA, long sB, long sC, long sColAux, long sResid) {
  __shared__ u16 As[128 * 64];
  __shared__ u16 Bs[128 * 64];
  const int id = blockIdx.x;
  const int xcd = id & 7, j = id >> 3;       // XCD = linear%8 (round-robin)
  const int bz = xcd * 2 + (j >> 6);         // 2 batches per XCD
  const int rr = j & 63;
  const int by = rr >> 3, bx = rr & 7;       // bx fastest -> A-tile reuse
  const u16* Ab = A + (long)bz * sA + (long)by * 128 * K;
  const u16* Bb = Bt + (long)bz * sB + (long)bx * 128 * K;
  const int tid = threadIdx.x;
  const int w = tid >> 6, l = tid & 63;
  const int wm = w >> 1, wn = w & 1;         // 2x2 wave grid, 64x64 per wave
  const int quad = l >> 4, lr = l & 15;
  const int r0 = tid >> 3;                   // staging row 0..31 (+32i)
  const int g = ((tid & 7) ^ (r0 & 7)) * 8;  // swizzled global chunk (elems)
  // frag read: global chunk c at LDS chunk c^(row&7); row&7 == lr&7.

  facc4 zero = {0.f, 0.f, 0.f, 0.f};
  facc4 acc[4][4];
#pragma unroll
  for (int i = 0; i < 4; ++i)
#pragma unroll
    for (int jj = 0; jj < 4; ++jj) acc[i][jj] = zero;

  for (int k0 = 0; k0 < K; k0 += 64) {
    __syncthreads();
#pragma unroll
    for (int i = 0; i < 4; ++i) {
      async16(Ab + (long)(r0 + 32 * i) * K + k0 + g, &As[i * 2048 + tid * 8]);
      async16(Bb + (long)(r0 + 32 * i) * K + k0 + g, &Bs[i * 2048 + tid * 8]);
    }
    __syncthreads();
#pragma unroll
    for (int s = 0; s < 2; ++s) {
      frag8 af[4], bfr[4];
#pragma unroll
      for (int mt = 0; mt < 4; ++mt)
        af[mt] = *(const frag8*)&As[(wm * 64 + mt * 16 + lr) * 64 +
                                    (((s * 4 + quad) ^ (lr & 7)) * 8)];
#pragma unroll
      for (int nt = 0; nt < 4; ++nt)
        bfr[nt] = *(const frag8*)&Bs[(wn * 64 + nt * 16 + lr) * 64 +
                                     (((s * 4 + quad) ^ (lr & 7)) * 8)];
#pragma unroll
      for (int mt = 0; mt < 4; ++mt)
#pragma unroll
        for (int nt = 0; nt < 4; ++nt)
          acc[mt][nt] = __builtin_amdgcn_mfma_f32_16x16x32_bf16(af[mt], bfr[nt],
                                                                acc[mt][nt], 0, 0, 0);
    }
  }

  const int rowB = by * 128 + wm * 64;
  const int colB = bx * 128 + wn * 64;
#pragma unroll
  for (int mt = 0; mt < 4; ++mt) {
#pragma unroll
    for (int nt = 0; nt < 4; ++nt) {
      const int col = colB + nt * 16 + lr;
      float ca = 0.f;
      if (EPI != 0) ca = colAux[(long)bz * sColAux + col];
#pragma unroll
      for (int i = 0; i < 4; ++i) {
        const int row = rowB + mt * 16 + quad * 4 + i;   // C/D: col=lane&15, row=quad*4+reg
        const long off = (long)bz * sC + (long)row * N + col;
        const float v = acc[mt][nt][i];
        if (EPI == 0) {
          ((u16*)Cv)[off] = f2bf(v);
        } else {
          ((u16*)Cv)[off] = f2bf(v - ca + resid[(long)bz * sResid + (long)row * N + col]);
        }
      }
    }
  }
}

// ------------- MX-fp8 GEMM (scale=1.0): C[M,N] = A[M,K] * Bt[N,K]^T -------------
// BK=128 fp8, mfma_scale_f32_16x16x128_f8f6f4. XCD-aware tile remap:
// ORDER 0: bx fastest within XCD row-stripe (A-tile reuse)        -> K6
// ORDER 1: by fastest within XCD row-stripe (A-stripe L2-resident) -> K5
// EPI 2: fp8 store relu(v + colAux[col])                (h = relu(.+b1))
// EPI 3: fp32 store v + colAux[col] + bf16 resid[off]   (out = ffn + b2 + out1)
template <int EPI, int ORDER>
__global__ void __launch_bounds__(256)
gemm_f8(const u8* __restrict__ A, const u8* __restrict__ Bt, void* __restrict__ Cv,
        const float* __restrict__ colAux, const u16* __restrict__ resid,
        int N, int K) {
  __shared__ u8 As[128 * 128];
  __shared__ u8 Bs[128 * 128];
  const int gx = gridDim.x, gy = gridDim.y;
  const int L = blockIdx.y * gx + blockIdx.x;
  const int xcd = L & 7, i0 = L >> 3;
  const int rows = gy >> 3;                 // per-XCD row stripe
  int bx, by;
  if (ORDER == 0) { bx = i0 % gx; by = xcd * rows + i0 / gx; }
  else            { by = xcd * rows + (i0 % rows); bx = i0 / rows; }
  const u8* Ab = A + (long)by * 128 * K;
  const u8* Bb = Bt + (long)bx * 128 * K;
  const int tid = threadIdx.x;
  const int w = tid >> 6, l = tid & 63;
  const int wm = w >> 1, wn = w & 1;
  const int quad = l >> 4, lr = l & 15;
  const int sr = tid >> 3;                                   // staging row (0..31)
  const int sc = ((tid & 7) ^ ((tid >> 3) & 7)) * 16;        // swizzled global chunk (bytes)
  const int qb = ((2 * quad) ^ (lr & 7)) * 16;               // frag chunk byte offset

  facc4 zero = {0.f, 0.f, 0.f, 0.f};
  facc4 acc[4][4];
#pragma unroll
  for (int i = 0; i < 4; ++i)
#pragma unroll
    for (int j = 0; j < 4; ++j) acc[i][j] = zero;

  for (int k0 = 0; k0 < K; k0 += 128) {
    __syncthreads();
#pragma unroll
    for (int i = 0; i < 4; ++i) {
      async16(Ab + (long)(sr + 32 * i) * K + k0 + sc, &As[i * 4096 + tid * 16]);
      async16(Bb + (long)(sr + 32 * i) * K + k0 + sc, &Bs[i * 4096 + tid * 16]);
    }
    __syncthreads();
    i32x8 af[4], bfr[4];
#pragma unroll
    for (int mt = 0; mt < 4; ++mt) {
      const u8* base = &As[(wm * 64 + mt * 16 + lr) * 128];
      i32x4 lo = *(const i32x4*)(base + qb);
      i32x4 hi = *(const i32x4*)(base + (qb ^ 16));
      af[mt] = i32x8{lo.x, lo.y, lo.z, lo.w, hi.x, hi.y, hi.z, hi.w};
    }
#pragma unroll
    for (int nt = 0; nt < 4; ++nt) {
      const u8* base = &Bs[(wn * 64 + nt * 16 + lr) * 128];
      i32x4 lo = *(const i32x4*)(base + qb);
      i32x4 hi = *(const i32x4*)(base + (qb ^ 16));
      bfr[nt] = i32x8{lo.x, lo.y, lo.z, lo.w, hi.x, hi.y, hi.z, hi.w};
    }
#pragma unroll
    for (int mt = 0; mt < 4; ++mt)
#pragma unroll
      for (int nt = 0; nt < 4; ++nt)
        acc[mt][nt] = __builtin_amdgcn_mfma_scale_f32_16x16x128_f8f6f4(
            af[mt], bfr[nt], acc[mt][nt], 0, 0,   // cbsz=0 (A fp8), blgp=0 (B fp8)
            0, 0x7F7F7F7F, 0, 0x7F7F7F7F);        // E8M0 scale 127 -> 1.0
  }

  const int rowB = by * 128 + wm * 64;
  const int colB = bx * 128 + wn * 64;
#pragma unroll
  for (int mt = 0; mt < 4; ++mt) {
#pragma unroll
    for (int nt = 0; nt < 4; ++nt) {
      const int col = colB + nt * 16 + lr;
      const float ca = colAux[col];
#pragma unroll
      for (int i = 0; i < 4; ++i) {
        const int row = rowB + mt * 16 + quad * 4 + i;
        const long off = (long)row * N + col;
        const float v = acc[mt][nt][i] + ca;
        if (EPI == 2) {
          ((u8*)Cv)[off] = f2fp8(fmaxf(v, 0.f));
        } else {
          ((float*)Cv)[off] = v + bf2f(resid[off]);
        }
      }
    }
  }
}

// ------------- column logsumexp over n (axis=1) of bf16 logits [b][n][s] --------
#define NCH 8
__global__ void lse_partial(const u16* __restrict__ logits, float* __restrict__ pm,
                            float* __restrict__ pl) {
  const int s = blockIdx.x * 256 + threadIdx.x;
  const int ch = blockIdx.y, b = blockIdx.z;
  const u16* p = logits + ((long)b << 20) + s;
  float m = -1e30f, lsum = 0.f;
  const int n0 = ch * (NKG / NCH);
  for (int n = n0; n < n0 + NKG / NCH; ++n) {
    const float x = bf2f(p[(long)n << 10]);
    const float nm = fmaxf(m, x);
    lsum = lsum * __expf(m - nm) + __expf(x - nm);
    m = nm;
  }
  const int idx = ((b << 3) + ch) * SLM + s;
  pm[idx] = m; pl[idx] = lsum;
}

__global__ void lse_combine(const float* __restrict__ pm, const float* __restrict__ pl,
                            float* __restrict__ L) {
  const int s = blockIdx.x * 256 + threadIdx.x;
  const int b = blockIdx.y;
  float M = -1e30f;
#pragma unroll
  for (int ch = 0; ch < NCH; ++ch) M = fmaxf(M, pm[((b << 3) + ch) * SLM + s]);
  float sum = 0.f;
#pragma unroll
  for (int ch = 0; ch < NCH; ++ch) {
    const int idx = ((b << 3) + ch) * SLM + s;
    sum += pl[idx] * __expf(pm[idx] - M);
  }
  L[b * SLM + s] = M + __logf(sum);
}

// ------------- c[b][d] = sum_s L[b][s] * lm_bf[b][s][d] -------------------------
__global__ void c_partial(const u16* __restrict__ lm, const float* __restrict__ L,
                          float* __restrict__ pc) {
  const int d = blockIdx.x * 256 + threadIdx.x;
  const int ch = blockIdx.y, b = blockIdx.z;
  const u16* lp = lm + ((long)b << 20);
  const float* Lp = L + (b << 10);
  float acc = 0.f;
  const int s0 = ch * (SLM / NCH);
  for (int s = s0; s < s0 + SLM / NCH; ++s)
    acc = fmaf(Lp[s], bf2f(lp[((long)s << 10) + d]), acc);
  pc[((b << 3) + ch) * DD + d] = acc;
}

__global__ void c_combine(const float* __restrict__ pc, float* __restrict__ c) {
  const int d = blockIdx.x * 256 + threadIdx.x;
  const int b = blockIdx.y;
  float s = 0.f;
#pragma unroll
  for (int ch = 0; ch < NCH; ++ch) s += pc[((b << 3) + ch) * DD + d];
  c[(b << 10) + d] = s;
}

// ------------- row LayerNorm over D=1024, bf16 in -> fp8 out --------------------
__global__ void layernorm_rows(const u16* __restrict__ x, const float* __restrict__ gamma,
                               const float* __restrict__ beta, u8* __restrict__ y) {
  const long row = blockIdx.x;
  const int t = threadIdx.x;
  const ushort4 u = ((const ushort4*)(x + (row << 10)))[t];
  float4 v;
  v.x = bf2f(u.x); v.y = bf2f(u.y); v.z = bf2f(u.z); v.w = bf2f(u.w);
  float s = v.x + v.y + v.z + v.w;
  float q = v.x * v.x + v.y * v.y + v.z * v.z + v.w * v.w;
#pragma unroll
  for (int off = 32; off > 0; off >>= 1) {
    s += __shfl_xor(s, off);
    q += __shfl_xor(q, off);
  }
  __shared__ float ss[4], qq[4];
  if ((t & 63) == 0) { ss[t >> 6] = s; qq[t >> 6] = q; }
  __syncthreads();
  s = ss[0] + ss[1] + ss[2] + ss[3];
  q = qq[0] + qq[1] + qq[2] + qq[3];
  const float mu = s * (1.f / 1024.f);
  const float rs = rsqrtf(q * (1.f / 1024.f) - mu * mu + 1e-6f);
  const float4 g = ((const float4*)gamma)[t];
  const float4 bb = ((const float4*)beta)[t];
  int p = __builtin_amdgcn_cvt_pk_fp8_f32((v.x - mu) * rs * g.x + bb.x,
                                          (v.y - mu) * rs * g.y + bb.y, 0, false);
  p = __builtin_amdgcn_cvt_pk_fp8_f32((v.z - mu) * rs * g.z + bb.z,
                                      (v.w - mu) * rs * g.w + bb.w, p, true);
  ((int*)(y + (row << 10)))[t] = p;
}

extern "C" void kernel_launch(void* const* d_in, const int* in_sizes, int n_in,
                              void* d_out, int out_size, void* d_ws, size_t ws_size,
                              hipStream_t stream) {
  (void)in_sizes; (void)n_in; (void)out_size;
  const float* kg = (const float*)d_in[0];
  const float* lm = (const float*)d_in[1];
  // d_in[2] attention_mask: log(mask+eps) is constant along the softmax axis
  // (axis=1) and cancels exactly in log_softmax -> unused.
  const float* W1 = (const float*)d_in[3];
  const float* b1 = (const float*)d_in[4];
  const float* W2 = (const float*)d_in[5];
  const float* b2 = (const float*)d_in[6];
  const float* gamma = (const float*)d_in[7];
  const float* beta = (const float*)d_in[8];
  float* out = (float*)d_out;
  char* ws = (char*)d_ws;

  const long SZ = 33554432;  // 32MB: one [16][1024][1024] bf16 tensor
  // Lifetimes: kg_bf,lm_bf through K1; lmT,logits through K3; then reuse.
  u16* kg_bf   = (u16*)(ws);                 // [b][n][d] bf16, K1
  u16* lm_bf   = (u16*)(ws + SZ);            // [b][s][d] bf16, K1 + c_partial
  u16* lmT     = (u16*)(ws + 2 * SZ);        // [b][d][s] bf16, K3
  u16* logits  = (u16*)(ws + 3 * SZ);        // [b][n][s] bf16, K2/K3
  u16* out1_bf = (u16*)(ws);                 // [b][n][d] bf16, K3->K4,K6 (reuses kg_bf)
  u8*  h       = (u8*)(ws + SZ);             // [16384][4096] fp8 64MB, K5->K6 (reuses lm_bf+lmT)
  u8*  out1n   = (u8*)(ws + 3 * SZ);         // [16384][1024] fp8 16MB, K4->K5 (reuses logits)
  u8*  W1t     = (u8*)(ws + 4 * SZ);                 // [H][D] fp8, 4MB
  u8*  W2t     = (u8*)(ws + 4 * SZ + 4194304);       // [D][H] fp8, 4MB
  char* smalls = ws + 4 * SZ + 8388608;
  float* Lse  = (float*)(smalls);
  float* cvec = (float*)(smalls + 65536);
  float* pm   = (float*)(smalls + 131072);
  float* pl   = (float*)(smalls + 131072 + 524288);
  float* pc   = (float*)(smalls + 131072 + 1048576);

  if (ws_size < (size_t)(4 * SZ + 8388608 + 131072 + 1572864)) return;  // ~144MB

  // Stage 0: casts & transposes
  cast_bf16<<<16384, 256, 0, stream>>>(kg, kg_bf);
  lm_prep<<<dim3(32, 32, 16), 256, 0, stream>>>(lm, lm_bf, lmT);
  transpose_cast_fp8<<<dim3(128, 32, 1), 256, 0, stream>>>(W1, W1t, DD, HH);
  transpose_cast_fp8<<<dim3(32, 128, 1), 256, 0, stream>>>(W2, W2t, HH, DD);

  // K1: logits = kg @ lm^T  (bf16 out)
  gemm_bt<0><<<1024, 256, 0, stream>>>(kg_bf, lm_bf, logits, nullptr, nullptr,
                                       SLM, DD, 1048576, 1048576, 1048576, 0, 0);
  // K2: L[b,s] = logsumexp_n logits ; c[b,d] = sum_s L*lm
  lse_partial<<<dim3(4, NCH, 16), 256, 0, stream>>>(logits, pm, pl);
  lse_combine<<<dim3(4, 16), 256, 0, stream>>>(pm, pl, Lse);
  c_partial<<<dim3(4, NCH, 16), 256, 0, stream>>>(lm_bf, Lse, pc);
  c_combine<<<dim3(4, 16), 256, 0, stream>>>(pc, cvec);
  // K3: out1 = logits @ lm - c + kg   (bf16, into ws)
  gemm_bt<1><<<1024, 256, 0, stream>>>(logits, lmT, out1_bf, cvec, kg,
                                       DD, SLM, 1048576, 1048576, 1048576, 1024, 1048576);
  // K4: layernorm rows -> fp8
  layernorm_rows<<<16384, 256, 0, stream>>>(out1_bf, gamma, beta, out1n);
  // K5: h = relu(out1n @ W1 + b1)  (fp8 in/out, MX-fp8 MFMA, A-stripe-resident order)
  gemm_f8<2, 1><<<dim3(32, 128, 1), 256, 0, stream>>>(out1n, W1t, h, b1, nullptr, HH, DD);
  // K6: out = h @ W2 + b2 + out1   (fp32 to d_out, A-tile-reuse order)
  gemm_f8<3, 0><<<dim3(8, 128, 1), 256, 0, stream>>>(h, W2t, out, b2, out1_bf, DD, HH);
}

// Round 4
// 510.682 us; speedup vs baseline: 1.5823x; 1.0036x over previous
//
#include <hip/hip_runtime.h>
#include <stdint.h>

// Problem constants
#define BB 16
#define NKG 1024
#define SLM 1024
#define DD 1024
#define HH 4096

typedef unsigned short u16;
typedef uint8_t u8;
typedef __attribute__((ext_vector_type(8))) short frag8;   // 8 bf16 in 4 VGPRs
typedef __attribute__((ext_vector_type(4))) float facc4;   // MFMA accumulator
typedef __attribute__((ext_vector_type(4))) int i32x4;
typedef __attribute__((ext_vector_type(8))) int i32x8;     // 32B fp8 A/B operand

__device__ __forceinline__ u16 f2bf(float f) {
  union { float f; unsigned u; } c; c.f = f;
  return (u16)((c.u + 0x7fffu + ((c.u >> 16) & 1u)) >> 16);  // RNE
}
__device__ __forceinline__ float bf2f(u16 h) {
  union { unsigned u; float f; } c; c.u = ((unsigned)h) << 16;
  return c.f;
}
__device__ __forceinline__ u8 f2fp8(float f) {
  int p = __builtin_amdgcn_cvt_pk_fp8_f32(f, f, 0, false);  // OCP e4m3 on gfx950
  return (u8)(p & 0xff);
}

// async global->LDS, 16B per lane. LDS dest must be wave-uniform base + lane*16.
__device__ __forceinline__ void async16(const void* g, void* l) {
  __builtin_amdgcn_global_load_lds(
      (__attribute__((address_space(1))) void*)(void*)(g),
      (__attribute__((address_space(3))) void*)(void*)(l), 16, 0, 0);
}

// ---------------- elementwise cast fp32 -> bf16 (float4 vectorized) -------------
__global__ void cast_bf16(const float* __restrict__ in, u16* __restrict__ out) {
  const long i = ((long)blockIdx.x * 256 + threadIdx.x) * 4;
  const float4 v = *(const float4*)(in + i);
  ushort4 o;
  o.x = f2bf(v.x); o.y = f2bf(v.y); o.z = f2bf(v.z); o.w = f2bf(v.w);
  *(ushort4*)(out + i) = o;
}

// ------- fused: lm fp32 [b][s][d] -> lm_bf (same layout) + lmT [b][d][s] --------
__global__ void lm_prep(const float* __restrict__ in, u16* __restrict__ straight,
                        u16* __restrict__ transposed) {
  __shared__ u16 tile[32][33];
  const int bz = blockIdx.z;
  const float* ip = in + ((long)bz << 20);
  u16* sp = straight + ((long)bz << 20);
  u16* tp = transposed + ((long)bz << 20);
  const int c0 = blockIdx.x * 32, r0 = blockIdx.y * 32;  // c over d, r over s
  const int tx = threadIdx.x & 31, ty = threadIdx.x >> 5;
#pragma unroll
  for (int i = 0; i < 32; i += 8) {
    const u16 v = f2bf(ip[(long)(r0 + ty + i) * DD + c0 + tx]);
    sp[(long)(r0 + ty + i) * DD + c0 + tx] = v;
    tile[ty + i][tx] = v;
  }
  __syncthreads();
#pragma unroll
  for (int i = 0; i < 32; i += 8)
    tp[(long)(c0 + ty + i) * SLM + r0 + tx] = tile[tx][ty + i];
}

// ---------------- transpose + cast: in fp32 [R][C] -> out fp8 [C][R] ------------
__global__ void transpose_cast_fp8(const float* __restrict__ in, u8* __restrict__ out,
                                   int R, int C) {
  __shared__ u8 tile[32][36];
  const int c0 = blockIdx.x * 32, r0 = blockIdx.y * 32;
  const int tx = threadIdx.x & 31, ty = threadIdx.x >> 5;
#pragma unroll
  for (int i = 0; i < 32; i += 8)
    tile[ty + i][tx] = f2fp8(in[(long)(r0 + ty + i) * C + c0 + tx]);
  __syncthreads();
#pragma unroll
  for (int i = 0; i < 32; i += 8)
    out[(long)(c0 + ty + i) * R + r0 + tx] = tile[tx][ty + i];
}

// --------- bf16 GEMM, MTx128 tile, BK=64, swizzled LDS, XCD-batched decode ------
// Grid: linear; each XCD owns 2 whole batches (per-batch M=N=1024, K=1024).
// EPI 0: store bf16 (logits)
// EPI 1: bf16 store: v - colAux[b,col] + resid[b,row,col]   (out1 = GEMM - c + kg)
template <int EPI, int MT>
__global__ void __launch_bounds__(256)
gemm_bt(const u16* __restrict__ A, const u16* __restrict__ Bt, void* __restrict__ Cv,
        const float* __restrict__ colAux, const float* __restrict__ resid,
        int N, int K, long sA, long sB, long sC, long sColAux, long sResid) {
  constexpr int MFR = MT / 32;              // 16-row frags per wave along M
  __shared__ u16 As[MT * 64];
  __shared__ u16 Bs[128 * 64];
  const int id = blockIdx.x;
  const int xcd = id & 7, j = id >> 3;      // XCD = linear%8 (round-robin)
  constexpr int TPB = (1024 / MT) * 8;      // tiles per batch
  const int bz = xcd * 2 + (j / TPB);       // 2 batches per XCD
  const int rr = j % TPB;
  const int by = rr >> 3, bx = rr & 7;      // bx fastest -> A-tile reuse
  const u16* Ab = A + (long)bz * sA + (long)by * MT * K;
  const u16* Bb = Bt + (long)bz * sB + (long)bx * 128 * K;
  const int tid = threadIdx.x;
  const int w = tid >> 6, l = tid & 63;
  const int wm = w >> 1, wn = w & 1;         // 2x2 wave grid
  const int quad = l >> 4, lr = l & 15;
  const int r0 = tid >> 3;                   // staging row 0..31 (+32i)
  const int g = ((tid & 7) ^ (r0 & 7)) * 8;  // swizzled global chunk (elems)
  // frag read: global chunk c at LDS chunk c^(row&7); row&7 == lr&7.

  facc4 zero = {0.f, 0.f, 0.f, 0.f};
  facc4 acc[MFR][4];
#pragma unroll
  for (int i = 0; i < MFR; ++i)
#pragma unroll
    for (int jj = 0; jj < 4; ++jj) acc[i][jj] = zero;

  for (int k0 = 0; k0 < K; k0 += 64) {
    __syncthreads();
#pragma unroll
    for (int i = 0; i < MFR; ++i)
      async16(Ab + (long)(r0 + 32 * i) * K + k0 + g, &As[i * 2048 + tid * 8]);
#pragma unroll
    for (int i = 0; i < 4; ++i)
      async16(Bb + (long)(r0 + 32 * i) * K + k0 + g, &Bs[i * 2048 + tid * 8]);
    __syncthreads();
#pragma unroll
    for (int s = 0; s < 2; ++s) {
      frag8 af[MFR], bfr[4];
#pragma unroll
      for (int mt = 0; mt < MFR; ++mt)
        af[mt] = *(const frag8*)&As[(wm * (MT / 2) + mt * 16 + lr) * 64 +
                                    (((s * 4 + quad) ^ (lr & 7)) * 8)];
#pragma unroll
      for (int nt = 0; nt < 4; ++nt)
        bfr[nt] = *(const frag8*)&Bs[(wn * 64 + nt * 16 + lr) * 64 +
                                     (((s * 4 + quad) ^ (lr & 7)) * 8)];
#pragma unroll
      for (int mt = 0; mt < MFR; ++mt)
#pragma unroll
        for (int nt = 0; nt < 4; ++nt)
          acc[mt][nt] = __builtin_amdgcn_mfma_f32_16x16x32_bf16(af[mt], bfr[nt],
                                                                acc[mt][nt], 0, 0, 0);
    }
  }

  const int rowB = by * MT + wm * (MT / 2);
  const int colB = bx * 128 + wn * 64;
#pragma unroll
  for (int mt = 0; mt < MFR; ++mt) {
#pragma unroll
    for (int nt = 0; nt < 4; ++nt) {
      const int col = colB + nt * 16 + lr;
      float ca = 0.f;
      if (EPI != 0) ca = colAux[(long)bz * sColAux + col];
#pragma unroll
      for (int i = 0; i < 4; ++i) {
        const int row = rowB + mt * 16 + quad * 4 + i;   // C/D: col=lane&15, row=quad*4+reg
        const long off = (long)bz * sC + (long)row * N + col;
        const float v = acc[mt][nt][i];
        if (EPI == 0) {
          ((u16*)Cv)[off] = f2bf(v);
        } else {
          ((u16*)Cv)[off] = f2bf(v - ca + resid[(long)bz * sResid + (long)row * N + col]);
        }
      }
    }
  }
}

// ------------- MX-fp8 GEMM (scale=1.0): C[M,N] = A[M,K] * Bt[N,K]^T -------------
// BK=128 fp8, mfma_scale_f32_16x16x128_f8f6f4. MTx128 tile. XCD-aware remap:
// ORDER 0: bx fastest within XCD row-stripe (B L2-resident, A streamed) -> K6
// ORDER 1: by fastest within XCD row-stripe (A-stripe L2-resident)      -> K5
// EPI 2: fp8 store relu(v + colAux[col])                (h = relu(.+b1))
// EPI 3: fp32 store v + colAux[col] + bf16 resid[off]   (out = ffn + b2 + out1)
template <int EPI, int ORDER, int MT>
__global__ void __launch_bounds__(256)
gemm_f8(const u8* __restrict__ A, const u8* __restrict__ Bt, void* __restrict__ Cv,
        const float* __restrict__ colAux, const u16* __restrict__ resid,
        int N, int K) {
  constexpr int MFR = MT / 32;
  __shared__ u8 As[MT * 128];
  __shared__ u8 Bs[128 * 128];
  const int gx = gridDim.x, gy = gridDim.y;
  const int L = blockIdx.y * gx + blockIdx.x;
  const int xcd = L & 7, i0 = L >> 3;
  const int rows = gy >> 3;                 // per-XCD row stripe
  int bx, by;
  if (ORDER == 0) { bx = i0 % gx; by = xcd * rows + i0 / gx; }
  else            { by = xcd * rows + (i0 % rows); bx = i0 / rows; }
  const u8* Ab = A + (long)by * MT * K;
  const u8* Bb = Bt + (long)bx * 128 * K;
  const int tid = threadIdx.x;
  const int w = tid >> 6, l = tid & 63;
  const int wm = w >> 1, wn = w & 1;
  const int quad = l >> 4, lr = l & 15;
  const int sr = tid >> 3;                                   // staging row (0..31)
  const int sc = ((tid & 7) ^ (sr & 7)) * 16;                // swizzled global chunk (bytes)
  const int qb = ((2 * quad) ^ (lr & 7)) * 16;               // frag chunk byte offset

  facc4 zero = {0.f, 0.f, 0.f, 0.f};
  facc4 acc[MFR][4];
#pragma unroll
  for (int i = 0; i < MFR; ++i)
#pragma unroll
    for (int j = 0; j < 4; ++j) acc[i][j] = zero;

  for (int k0 = 0; k0 < K; k0 += 128) {
    __syncthreads();
#pragma unroll
    for (int i = 0; i < MFR; ++i)
      async16(Ab + (long)(sr + 32 * i) * K + k0 + sc, &As[i * 4096 + tid * 16]);
#pragma unroll
    for (int i = 0; i < 4; ++i)
      async16(Bb + (long)(sr + 32 * i) * K + k0 + sc, &Bs[i * 4096 + tid * 16]);
    __syncthreads();
    i32x8 af[MFR], bfr[4];
#pragma unroll
    for (int mt = 0; mt < MFR; ++mt) {
      const u8* base = &As[(wm * (MT / 2) + mt * 16 + lr) * 128];
      i32x4 lo = *(const i32x4*)(base + qb);
      i32x4 hi = *(const i32x4*)(base + (qb ^ 16));
      af[mt] = i32x8{lo.x, lo.y, lo.z, lo.w, hi.x, hi.y, hi.z, hi.w};
    }
#pragma unroll
    for (int nt = 0; nt < 4; ++nt) {
      const u8* base = &Bs[(wn * 64 + nt * 16 + lr) * 128];
      i32x4 lo = *(const i32x4*)(base + qb);
      i32x4 hi = *(const i32x4*)(base + (qb ^ 16));
      bfr[nt] = i32x8{lo.x, lo.y, lo.z, lo.w, hi.x, hi.y, hi.z, hi.w};
    }
#pragma unroll
    for (int mt = 0; mt < MFR; ++mt)
#pragma unroll
      for (int nt = 0; nt < 4; ++nt)
        acc[mt][nt] = __builtin_amdgcn_mfma_scale_f32_16x16x128_f8f6f4(
            af[mt], bfr[nt], acc[mt][nt], 0, 0,   // cbsz=0 (A fp8), blgp=0 (B fp8)
            0, 0x7F7F7F7F, 0, 0x7F7F7F7F);        // E8M0 scale 127 -> 1.0
  }

  const int rowB = by * MT + wm * (MT / 2);
  const int colB = bx * 128 + wn * 64;
#pragma unroll
  for (int mt = 0; mt < MFR; ++mt) {
#pragma unroll
    for (int nt = 0; nt < 4; ++nt) {
      const int col = colB + nt * 16 + lr;
      const float ca = colAux[col];
#pragma unroll
      for (int i = 0; i < 4; ++i) {
        const int row = rowB + mt * 16 + quad * 4 + i;
        const long off = (long)row * N + col;
        const float v = acc[mt][nt][i] + ca;
        if (EPI == 2) {
          ((u8*)Cv)[off] = f2fp8(fmaxf(v, 0.f));
        } else {
          ((float*)Cv)[off] = v + bf2f(resid[off]);
        }
      }
    }
  }
}

// ------------- column logsumexp over n (axis=1) of bf16 logits [b][n][s] --------
#define NCH 8
__global__ void lse_partial(const u16* __restrict__ logits, float* __restrict__ pm,
                            float* __restrict__ pl) {
  const int s = blockIdx.x * 256 + threadIdx.x;
  const int ch = blockIdx.y, b = blockIdx.z;
  const u16* p = logits + ((long)b << 20) + s;
  float m = -1e30f, lsum = 0.f;
  const int n0 = ch * (NKG / NCH);
  for (int n = n0; n < n0 + NKG / NCH; ++n) {
    const float x = bf2f(p[(long)n << 10]);
    const float nm = fmaxf(m, x);
    lsum = lsum * __expf(m - nm) + __expf(x - nm);
    m = nm;
  }
  const int idx = ((b << 3) + ch) * SLM + s;
  pm[idx] = m; pl[idx] = lsum;
}

__global__ void lse_combine(const float* __restrict__ pm, const float* __restrict__ pl,
                            float* __restrict__ L) {
  const int s = blockIdx.x * 256 + threadIdx.x;
  const int b = blockIdx.y;
  float M = -1e30f;
#pragma unroll
  for (int ch = 0; ch < NCH; ++ch) M = fmaxf(M, pm[((b << 3) + ch) * SLM + s]);
  float sum = 0.f;
#pragma unroll
  for (int ch = 0; ch < NCH; ++ch) {
    const int idx = ((b << 3) + ch) * SLM + s;
    sum += pl[idx] * __expf(pm[idx] - M);
  }
  L[b * SLM + s] = M + __logf(sum);
}

// ------------- c[b][d] = sum_s L[b][s] * lm_bf[b][s][d] -------------------------
__global__ void c_partial(const u16* __restrict__ lm, const float* __restrict__ L,
                          float* __restrict__ pc) {
  const int d = blockIdx.x * 256 + threadIdx.x;
  const int ch = blockIdx.y, b = blockIdx.z;
  const u16* lp = lm + ((long)b << 20);
  const float* Lp = L + (b << 10);
  float acc = 0.f;
  const int s0 = ch * (SLM / NCH);
  for (int s = s0; s < s0 + SLM / NCH; ++s)
    acc = fmaf(Lp[s], bf2f(lp[((long)s << 10) + d]), acc);
  pc[((b << 3) + ch) * DD + d] = acc;
}

__global__ void c_combine(const float* __restrict__ pc, float* __restrict__ c) {
  const int d = blockIdx.x * 256 + threadIdx.x;
  const int b = blockIdx.y;
  float s = 0.f;
#pragma unroll
  for (int ch = 0; ch < NCH; ++ch) s += pc[((b << 3) + ch) * DD + d];
  c[(b << 10) + d] = s;
}

// ------------- row LayerNorm over D=1024, bf16 in -> fp8 out --------------------
__global__ void layernorm_rows(const u16* __restrict__ x, const float* __restrict__ gamma,
                               const float* __restrict__ beta, u8* __restrict__ y) {
  const long row = blockIdx.x;
  const int t = threadIdx.x;
  const ushort4 u = ((const ushort4*)(x + (row << 10)))[t];
  float4 v;
  v.x = bf2f(u.x); v.y = bf2f(u.y); v.z = bf2f(u.z); v.w = bf2f(u.w);
  float s = v.x + v.y + v.z + v.w;
  float q = v.x * v.x + v.y * v.y + v.z * v.z + v.w * v.w;
#pragma unroll
  for (int off = 32; off > 0; off >>= 1) {
    s += __shfl_xor(s, off);
    q += __shfl_xor(q, off);
  }
  __shared__ float ss[4], qq[4];
  if ((t & 63) == 0) { ss[t >> 6] = s; qq[t >> 6] = q; }
  __syncthreads();
  s = ss[0] + ss[1] + ss[2] + ss[3];
  q = qq[0] + qq[1] + qq[2] + qq[3];
  const float mu = s * (1.f / 1024.f);
  const float rs = rsqrtf(q * (1.f / 1024.f) - mu * mu + 1e-6f);
  const float4 g = ((const float4*)gamma)[t];
  const float4 bb = ((const float4*)beta)[t];
  int p = __builtin_amdgcn_cvt_pk_fp8_f32((v.x - mu) * rs * g.x + bb.x,
                                          (v.y - mu) * rs * g.y + bb.y, 0, false);
  p = __builtin_amdgcn_cvt_pk_fp8_f32((v.z - mu) * rs * g.z + bb.z,
                                      (v.w - mu) * rs * g.w + bb.w, p, true);
  ((int*)(y + (row << 10)))[t] = p;
}

extern "C" void kernel_launch(void* const* d_in, const int* in_sizes, int n_in,
                              void* d_out, int out_size, void* d_ws, size_t ws_size,
                              hipStream_t stream) {
  (void)in_sizes; (void)n_in; (void)out_size;
  const float* kg = (const float*)d_in[0];
  const float* lm = (const float*)d_in[1];
  // d_in[2] attention_mask: log(mask+eps) is constant along the softmax axis
  // (axis=1) and cancels exactly in log_softmax -> unused.
  const float* W1 = (const float*)d_in[3];
  const float* b1 = (const float*)d_in[4];
  const float* W2 = (const float*)d_in[5];
  const float* b2 = (const float*)d_in[6];
  const float* gamma = (const float*)d_in[7];
  const float* beta = (const float*)d_in[8];
  float* out = (float*)d_out;
  char* ws = (char*)d_ws;

  const long SZ = 33554432;  // 32MB: one [16][1024][1024] bf16 tensor
  // Lifetimes: kg_bf,lm_bf through K1; lmT,logits through K3; then reuse.
  u16* kg_bf   = (u16*)(ws);                 // [b][n][d] bf16, K1
  u16* lm_bf   = (u16*)(ws + SZ);            // [b][s][d] bf16, K1 + c_partial
  u16* lmT     = (u16*)(ws + 2 * SZ);        // [b][d][s] bf16, K3
  u16* logits  = (u16*)(ws + 3 * SZ);        // [b][n][s] bf16, K2/K3
  u16* out1_bf = (u16*)(ws);                 // [b][n][d] bf16, K3->K4,K6 (reuses kg_bf)
  u8*  h       = (u8*)(ws + SZ);             // [16384][4096] fp8 64MB, K5->K6 (reuses lm_bf+lmT)
  u8*  out1n   = (u8*)(ws + 3 * SZ);         // [16384][1024] fp8 16MB, K4->K5 (reuses logits)
  u8*  W1t     = (u8*)(ws + 4 * SZ);                 // [H][D] fp8, 4MB
  u8*  W2t     = (u8*)(ws + 4 * SZ + 4194304);       // [D][H] fp8, 4MB
  char* smalls = ws + 4 * SZ + 8388608;
  float* Lse  = (float*)(smalls);
  float* cvec = (float*)(smalls + 65536);
  float* pm   = (float*)(smalls + 131072);
  float* pl   = (float*)(smalls + 131072 + 524288);
  float* pc   = (float*)(smalls + 131072 + 1048576);

  if (ws_size < (size_t)(4 * SZ + 8388608 + 131072 + 1572864)) return;  // ~144MB

  // Stage 0: casts & transposes
  cast_bf16<<<16384, 256, 0, stream>>>(kg, kg_bf);
  lm_prep<<<dim3(32, 32, 16), 256, 0, stream>>>(lm, lm_bf, lmT);
  transpose_cast_fp8<<<dim3(128, 32, 1), 256, 0, stream>>>(W1, W1t, DD, HH);
  transpose_cast_fp8<<<dim3(32, 128, 1), 256, 0, stream>>>(W2, W2t, HH, DD);

  // K1: logits = kg @ lm^T  (bf16 out) — 64-row tiles, 2048 blocks
  gemm_bt<0, 64><<<2048, 256, 0, stream>>>(kg_bf, lm_bf, logits, nullptr, nullptr,
                                           SLM, DD, 1048576, 1048576, 1048576, 0, 0);
  // K2: L[b,s] = logsumexp_n logits ; c[b,d] = sum_s L*lm
  lse_partial<<<dim3(4, NCH, 16), 256, 0, stream>>>(logits, pm, pl);
  lse_combine<<<dim3(4, 16), 256, 0, stream>>>(pm, pl, Lse);
  c_partial<<<dim3(4, NCH, 16), 256, 0, stream>>>(lm_bf, Lse, pc);
  c_combine<<<dim3(4, 16), 256, 0, stream>>>(pc, cvec);
  // K3: out1 = logits @ lm - c + kg   (bf16, into ws) — 64-row tiles
  gemm_bt<1, 64><<<2048, 256, 0, stream>>>(logits, lmT, out1_bf, cvec, kg,
                                           DD, SLM, 1048576, 1048576, 1048576, 1024, 1048576);
  // K4: layernorm rows -> fp8
  layernorm_rows<<<16384, 256, 0, stream>>>(out1_bf, gamma, beta, out1n);
  // K5: h = relu(out1n @ W1 + b1)  (fp8, MX MFMA, 128-tiles, A-stripe-resident order)
  gemm_f8<2, 1, 128><<<dim3(32, 128, 1), 256, 0, stream>>>(out1n, W1t, h, b1, nullptr, HH, DD);
  // K6: out = h @ W2 + b2 + out1   (fp32 to d_out, 64-row tiles, B-resident order)
  gemm_f8<3, 0, 64><<<dim3(8, 256, 1), 256, 0, stream>>>(h, W2t, out, b2, out1_bf, DD, HH);
}